// Round 1
// 606.283 us; speedup vs baseline: 1.0637x; 1.0637x over previous
//
#include <hip/hip_runtime.h>
#include <hip/hip_bf16.h>

// Problem constants
#define BATCH 32
#define C 160
#define H 112
#define W 112
#define HW (H * W)            // 12544
#define NT 7                  // N-tiles per row: 7*16 = 112

typedef __bf16 bf16_t;
typedef bf16_t bf16x8 __attribute__((ext_vector_type(8)));
typedef float f32x4 __attribute__((ext_vector_type(4)));

// Workspace layout (bytes).
// P is stored as [b][kb(5)][y][x][32ch] bf16, channels within a 32-block in the
// PERMUTED order pos = quad*8+jj  <->  chan = (jj<4) ? quad*4+jj : 16+quad*4+(jj-4)
// so stage2 B-fragments are single dwordx4 loads and stage1 epilogue stores are
// single dwordx4 stores (both 1KB/wave/instr, fully coalesced).
#define P_BYTES   ((size_t)BATCH * C * HW * 2)   // 128,450,560
#define WALL_OFF  (P_BYTES)
#define WFRAG_B   (10 * 5 * 64 * 8 * 2)          // 51,200 per weight matrix
#define WFUSE_OFF (WALL_OFF + WFRAG_B)
#define BN2_OFF   (WFUSE_OFF + WFRAG_B)          // float2 {scale, shift} per channel
#define BALL_OFF  (BN2_OFF + C * 8)              // stacked branch bias, 160 f32

// ---------------------------------------------------------------------------
// Prep: bn scale/shift; pack W_all (natural k order) and W_fuse (permuted k
// order matching P's in-block channel permutation) into MFMA A-fragment order:
// frag idx = ((mt*5 + ks)*64 + lane)*8 + j, m = mt*16 + (lane&15).
// ---------------------------------------------------------------------------
__global__ __launch_bounds__(256) void prep_kernel(
    const float* __restrict__ Wt, const float* __restrict__ Wb,
    const float* __restrict__ Wr, const float* __restrict__ Wl,
    const float* __restrict__ Wc,
    const float* __restrict__ bt, const float* __restrict__ bb,
    const float* __restrict__ br, const float* __restrict__ bl,
    const float* __restrict__ bc,
    const float* __restrict__ Wfuse,
    const float* __restrict__ gamma, const float* __restrict__ beta,
    const float* __restrict__ mean, const float* __restrict__ var,
    char* __restrict__ ws)
{
    bf16_t* wallf  = (bf16_t*)(ws + WALL_OFF);
    bf16_t* wfusef = (bf16_t*)(ws + WFUSE_OFF);
    float2* bn2 = (float2*)(ws + BN2_OFF);
    float*  ball = (float*)(ws + BALL_OFF);

    const float* Wbr[5] = {Wt, Wb, Wr, Wl, Wc};
    const float* bbr[5] = {bt, bb, br, bl, bc};

    int tid = blockIdx.x * blockDim.x + threadIdx.x;
    int nth = gridDim.x * blockDim.x;

    for (int idx = tid; idx < 10 * 5 * 64 * 8; idx += nth) {
        int j    = idx & 7;
        int lane = (idx >> 3) & 63;
        int rest = idx >> 9;
        int ks   = rest % 5;
        int mt   = rest / 5;
        int m  = mt * 16 + (lane & 15);
        int q  = lane >> 4;
        // W_all: natural k order (stage1 loads x directly by channel)
        int k_nat = ks * 32 + q * 8 + j;
        wallf[idx] = (bf16_t)Wbr[m >> 5][(m & 31) * C + k_nat];
        // W_fuse: permuted k order matching P's in-block channel layout
        int chan32 = (j < 4) ? (q * 4 + j) : (16 + q * 4 + (j - 4));
        wfusef[idx] = (bf16_t)Wfuse[m * C + ks * 32 + chan32];
    }
    for (int c = tid; c < C; c += nth) {
        float s = gamma[c] * rsqrtf(var[c] + 1e-5f);
        bn2[c] = make_float2(s, beta[c] - mean[c] * s);
        ball[c] = bbr[c >> 5][c & 31];
    }
}

// ---------------------------------------------------------------------------
// Stage 1: P = W_all @ gelu(bn(x)) + b_all, P in permuted [b][kb][y][x][32] bf16.
// One wave per (b, y, 16-px tile). No LDS: x loaded straight into B-fragments.
// v2: all 40 channel loads hoisted up front (5x deeper MLP), and exact-GELU
// computed via branchless A&S-7.1.26 erf (|err|<=1.5e-7, ~16 VALU ops vs the
// divergent ~60-90-op OCML erff path).
// ---------------------------------------------------------------------------
__global__ __launch_bounds__(256) void stage1_kernel(
    const float* __restrict__ x, char* __restrict__ ws)
{
    const bf16_t* __restrict__ wallf = (const bf16_t*)(ws + WALL_OFF);
    const float2* __restrict__ bn2 = (const float2*)(ws + BN2_OFF);
    const float*  __restrict__ ball = (const float*)(ws + BALL_OFF);
    bf16_t* __restrict__ P = (bf16_t*)ws;

    int wid  = blockIdx.x * 4 + (threadIdx.x >> 6);
    int lane = threadIdx.x & 63;
    int b   = wid / (NT * H);
    int rem = wid - b * (NT * H);
    int y   = rem / NT;
    int t   = rem - y * NT;
    int nl = lane & 15, quad = lane >> 4;
    int px = t * 16 + nl;

    const float* xp = x + (size_t)b * C * HW + (size_t)y * W + px;

    // Issue ALL 40 channel loads before any compute: 40 outstanding loads/wave.
    float v[40];
#pragma unroll
    for (int i = 0; i < 40; ++i) {
        int ks = i >> 3, j = i & 7;
        v[i] = xp[(size_t)(ks * 32 + quad * 8 + j) * HW];
    }

    f32x4 acc[10];
#pragma unroll
    for (int mt = 0; mt < 10; ++mt)
        acc[mt] = *(const f32x4*)&ball[mt * 16 + quad * 4];

#pragma unroll
    for (int ks = 0; ks < 5; ++ks) {
        bf16x8 bfrag;
#pragma unroll
        for (int j = 0; j < 8; ++j) {
            int c = ks * 32 + quad * 8 + j;
            float2 sb = bn2[c];
            float h = v[ks * 8 + j] * sb.x + sb.y;
            // exact GELU via branchless rational erf (A&S 7.1.26):
            // erf(u) = sign(u) * (1 - poly(t)*exp(-u^2)), t = 1/(1+0.3275911|u|)
            float u  = h * 0.70710678118654752f;
            float au = __builtin_fabsf(u);
            float tt = __builtin_amdgcn_rcpf(__builtin_fmaf(0.3275911f, au, 1.0f));
            float poly = tt * __builtin_fmaf(tt,
                              __builtin_fmaf(tt,
                              __builtin_fmaf(tt,
                              __builtin_fmaf(tt, 1.061405429f, -1.453152027f),
                                                 1.421413741f),
                                                -0.284496736f),
                                                 0.254829592f);
            float e  = __builtin_amdgcn_exp2f(-au * au * 1.4426950408889634f);
            float er = __builtin_fmaf(-poly, e, 1.0f);
            er = __builtin_copysignf(er, u);
            h = 0.5f * h * (1.0f + er);
            bfrag[j] = (bf16_t)h;
        }
#pragma unroll
        for (int mt = 0; mt < 10; ++mt) {
            bf16x8 afrag = *(const bf16x8*)&wallf[((mt * 5 + ks) * 64 + lane) * 8];
            acc[mt] = __builtin_amdgcn_mfma_f32_16x16x32_bf16(afrag, bfrag, acc[mt], 0, 0, 0);
        }
    }

    // Epilogue: pack (acc[2kb], acc[2kb+1]) -> permuted 32-block, one 16B store per kb.
    size_t pb = (((size_t)(b * 5) * H + y) * W + px) * 32 + quad * 8;
#pragma unroll
    for (int kb = 0; kb < 5; ++kb) {
        bf16x8 o;
#pragma unroll
        for (int r = 0; r < 4; ++r) {
            o[r]     = (bf16_t)acc[kb * 2][r];       // chan kb*32 + quad*4 + r
            o[r + 4] = (bf16_t)acc[kb * 2 + 1][r];   // chan kb*32 + 16 + quad*4 + r
        }
        *(bf16x8*)&P[pb + (size_t)kb * HW * 32] = o;
    }
}

// ---------------------------------------------------------------------------
// Stage 2: out = W_fuse @ shift(P) + b_fuse. Shifts folded into P base address:
//   kb0 (t): (y+1,x)  kb1 (b): (y-1,x)  kb2 (r): (y,x-1)  kb3 (l): (y,x+1)  kb4: (y,x)
// Out-of-range -> zero fragment (drops branch bias at borders, matching pad).
// All shifted addresses are provably within the P region; masking is in-register.
// ---------------------------------------------------------------------------
__global__ __launch_bounds__(256) void stage2_kernel(
    char* __restrict__ ws, const float* __restrict__ bfuse,
    float* __restrict__ out)
{
    const bf16_t* __restrict__ wfusef = (const bf16_t*)(ws + WFUSE_OFF);
    const bf16_t* __restrict__ P = (const bf16_t*)ws;

    int wid  = blockIdx.x * 4 + (threadIdx.x >> 6);
    int lane = threadIdx.x & 63;
    int b   = wid / (NT * H);
    int rem = wid - b * (NT * H);
    int y   = rem / NT;
    int t   = rem - y * NT;
    int nl = lane & 15, quad = lane >> 4;
    int px = t * 16 + nl;

    f32x4 acc[10];
#pragma unroll
    for (int mt = 0; mt < 10; ++mt)
        acc[mt] = *(const f32x4*)&bfuse[mt * 16 + quad * 4];

    bf16x8 zero;
#pragma unroll
    for (int j = 0; j < 8; ++j) zero[j] = (bf16_t)0.0f;

    auto ldP = [&](int kb, int yy, int xx) -> bf16x8 {
        return *(const bf16x8*)&P[(((size_t)(b * 5 + kb) * H + yy) * W + xx) * 32 + quad * 8];
    };

    bf16x8 f[5];
    f[0] = ldP(0, y + 1, px); if (y + 1 >= H) f[0] = zero;
    f[1] = ldP(1, y - 1, px); if (y == 0)     f[1] = zero;
    f[2] = ldP(2, y, px - 1); if (px == 0)    f[2] = zero;
    f[3] = ldP(3, y, px + 1); if (px == W - 1) f[3] = zero;
    f[4] = ldP(4, y, px);

#pragma unroll
    for (int ks = 0; ks < 5; ++ks) {
#pragma unroll
        for (int mt = 0; mt < 10; ++mt) {
            bf16x8 afrag = *(const bf16x8*)&wfusef[((mt * 5 + ks) * 64 + lane) * 8];
            acc[mt] = __builtin_amdgcn_mfma_f32_16x16x32_bf16(afrag, f[ks], acc[mt], 0, 0, 0);
        }
    }

    size_t ob = (size_t)b * C * HW + (size_t)y * W + px;
#pragma unroll
    for (int mt = 0; mt < 10; ++mt) {
#pragma unroll
        for (int r = 0; r < 4; ++r) {
            int m = mt * 16 + quad * 4 + r;
            out[ob + (size_t)m * HW] = acc[mt][r];
        }
    }
}

// ---------------------------------------------------------------------------
extern "C" void kernel_launch(void* const* d_in, const int* in_sizes, int n_in,
                              void* d_out, int out_size, void* d_ws, size_t ws_size,
                              hipStream_t stream)
{
    const float* x     = (const float*)d_in[0];
    const float* gamma = (const float*)d_in[1];
    const float* beta  = (const float*)d_in[2];
    const float* mean  = (const float*)d_in[3];
    const float* var   = (const float*)d_in[4];
    const float* Wt    = (const float*)d_in[5];
    const float* bt    = (const float*)d_in[6];
    const float* Wb    = (const float*)d_in[7];
    const float* bb    = (const float*)d_in[8];
    const float* Wr    = (const float*)d_in[9];
    const float* br    = (const float*)d_in[10];
    const float* Wl    = (const float*)d_in[11];
    const float* bl    = (const float*)d_in[12];
    const float* Wc    = (const float*)d_in[13];
    const float* bc    = (const float*)d_in[14];
    const float* Wfuse = (const float*)d_in[15];
    const float* bfuse = (const float*)d_in[16];

    char* ws = (char*)d_ws;
    float* out = (float*)d_out;

    prep_kernel<<<64, 256, 0, stream>>>(Wt, Wb, Wr, Wl, Wc, bt, bb, br, bl, bc,
                                        Wfuse, gamma, beta, mean, var, ws);

    int nblocks = (BATCH * H * NT) / 4;   // 25088 waves / 4 waves per block
    stage1_kernel<<<nblocks, 256, 0, stream>>>(x, ws);
    stage2_kernel<<<nblocks, 256, 0, stream>>>(ws, bfuse, out);
}

// Round 2
// 590.078 us; speedup vs baseline: 1.0929x; 1.0275x over previous
//
#include <hip/hip_runtime.h>
#include <hip/hip_bf16.h>

// Problem constants
#define BATCH 32
#define C 160
#define H 112
#define W 112
#define HW (H * W)            // 12544
#define NT 7                  // N-tiles per row: 7*16 = 112
#define HP (H / 2)            // 56 row-pairs

typedef __bf16 bf16_t;
typedef bf16_t bf16x8 __attribute__((ext_vector_type(8)));
typedef float f32x4 __attribute__((ext_vector_type(4)));

// Workspace layout (bytes).
// P is stored as [b][kb(5)][y][x][32ch] bf16, channels within a 32-block in the
// PERMUTED order pos = quad*8+jj  <->  chan = (jj<4) ? quad*4+jj : 16+quad*4+(jj-4)
// so stage2 B-fragments are single dwordx4 loads and stage1 epilogue stores are
// single dwordx4 stores (both 1KB/wave/instr, fully coalesced).
#define P_BYTES   ((size_t)BATCH * C * HW * 2)   // 128,450,560
#define WALL_OFF  (P_BYTES)
#define WFRAG_B   (10 * 5 * 64 * 8 * 2)          // 51,200 per weight matrix
#define WFUSE_OFF (WALL_OFF + WFRAG_B)
#define BN2_OFF   (WFUSE_OFF + WFRAG_B)          // float2 {scale, shift} per channel
#define BALL_OFF  (BN2_OFF + C * 8)              // stacked branch bias, 160 f32

// Exact GELU via branchless A&S-7.1.26 erf (|err|<=1.5e-7 << bf16 quantum).
__device__ __forceinline__ float gelu_exact(float h) {
    float u  = h * 0.70710678118654752f;
    float au = __builtin_fabsf(u);
    float tt = __builtin_amdgcn_rcpf(__builtin_fmaf(0.3275911f, au, 1.0f));
    float poly = tt * __builtin_fmaf(tt,
                      __builtin_fmaf(tt,
                      __builtin_fmaf(tt,
                      __builtin_fmaf(tt, 1.061405429f, -1.453152027f),
                                         1.421413741f),
                                        -0.284496736f),
                                         0.254829592f);
    float e  = __builtin_amdgcn_exp2f(-au * au * 1.4426950408889634f);
    float er = __builtin_fmaf(-poly, e, 1.0f);
    er = __builtin_copysignf(er, u);
    return 0.5f * h * (1.0f + er);
}

// ---------------------------------------------------------------------------
// Prep: bn scale/shift; pack W_all (natural k order) and W_fuse (permuted k
// order matching P's in-block channel permutation) into MFMA A-fragment order:
// frag idx = ((mt*5 + ks)*64 + lane)*8 + j, m = mt*16 + (lane&15).
// ---------------------------------------------------------------------------
__global__ __launch_bounds__(256) void prep_kernel(
    const float* __restrict__ Wt, const float* __restrict__ Wb,
    const float* __restrict__ Wr, const float* __restrict__ Wl,
    const float* __restrict__ Wc,
    const float* __restrict__ bt, const float* __restrict__ bb,
    const float* __restrict__ br, const float* __restrict__ bl,
    const float* __restrict__ bc,
    const float* __restrict__ Wfuse,
    const float* __restrict__ gamma, const float* __restrict__ beta,
    const float* __restrict__ mean, const float* __restrict__ var,
    char* __restrict__ ws)
{
    bf16_t* wallf  = (bf16_t*)(ws + WALL_OFF);
    bf16_t* wfusef = (bf16_t*)(ws + WFUSE_OFF);
    float2* bn2 = (float2*)(ws + BN2_OFF);
    float*  ball = (float*)(ws + BALL_OFF);

    const float* Wbr[5] = {Wt, Wb, Wr, Wl, Wc};
    const float* bbr[5] = {bt, bb, br, bl, bc};

    int tid = blockIdx.x * blockDim.x + threadIdx.x;
    int nth = gridDim.x * blockDim.x;

    for (int idx = tid; idx < 10 * 5 * 64 * 8; idx += nth) {
        int j    = idx & 7;
        int lane = (idx >> 3) & 63;
        int rest = idx >> 9;
        int ks   = rest % 5;
        int mt   = rest / 5;
        int m  = mt * 16 + (lane & 15);
        int q  = lane >> 4;
        // W_all: natural k order (stage1 loads x directly by channel)
        int k_nat = ks * 32 + q * 8 + j;
        wallf[idx] = (bf16_t)Wbr[m >> 5][(m & 31) * C + k_nat];
        // W_fuse: permuted k order matching P's in-block channel layout
        int chan32 = (j < 4) ? (q * 4 + j) : (16 + q * 4 + (j - 4));
        wfusef[idx] = (bf16_t)Wfuse[m * C + ks * 32 + chan32];
    }
    for (int c = tid; c < C; c += nth) {
        float s = gamma[c] * rsqrtf(var[c] + 1e-5f);
        bn2[c] = make_float2(s, beta[c] - mean[c] * s);
        ball[c] = bbr[c >> 5][c & 31];
    }
}

// ---------------------------------------------------------------------------
// Stage 1: P = W_all @ gelu(bn(x)) + b_all, P in permuted [b][kb][y][x][32] bf16.
// v3: one wave per (b, ROW-PAIR, 16-px tile). Both rows' 80 x-loads issued up
// front and pinned with sched_barrier(0) so LLVM can't sink them (round-1
// failure: VGPR=76 proved the 40-load hoist was re-sunk). A-fragments (weights)
// loaded once and fed to BOTH rows' MFMA chains -> weight-load instrs per pixel
// halved, two independent MFMA dep-chains pipeline.
// ---------------------------------------------------------------------------
__global__ __launch_bounds__(256, 2) void stage1_kernel(
    const float* __restrict__ x, char* __restrict__ ws)
{
    const bf16_t* __restrict__ wallf = (const bf16_t*)(ws + WALL_OFF);
    const float2* __restrict__ bn2 = (const float2*)(ws + BN2_OFF);
    const float*  __restrict__ ball = (const float*)(ws + BALL_OFF);
    bf16_t* __restrict__ P = (bf16_t*)ws;

    int wid  = blockIdx.x * 4 + (threadIdx.x >> 6);
    int lane = threadIdx.x & 63;
    int b   = wid / (HP * NT);
    int rem = wid - b * (HP * NT);
    int yp  = rem / NT;
    int t   = rem - yp * NT;
    int y0  = yp * 2;
    int nl = lane & 15, quad = lane >> 4;
    int px = t * 16 + nl;

    const float* xp = x + (size_t)b * C * HW + (size_t)y0 * W + px;

    // Issue ALL 80 channel loads (both rows) before any compute; pin them.
    float v0[40], v1[40];
#pragma unroll
    for (int i = 0; i < 40; ++i) {
        int ks = i >> 3, j = i & 7;
        size_t off = (size_t)(ks * 32 + quad * 8 + j) * HW;
        v0[i] = xp[off];
        v1[i] = xp[off + W];
    }
    __builtin_amdgcn_sched_barrier(0);

    f32x4 acc0[10], acc1[10];
#pragma unroll
    for (int mt = 0; mt < 10; ++mt) {
        f32x4 bias = *(const f32x4*)&ball[mt * 16 + quad * 4];
        acc0[mt] = bias;
        acc1[mt] = bias;
    }

#pragma unroll
    for (int ks = 0; ks < 5; ++ks) {
        bf16x8 bfrag0, bfrag1;
#pragma unroll
        for (int j = 0; j < 8; ++j) {
            int c = ks * 32 + quad * 8 + j;
            float2 sb = bn2[c];
            bfrag0[j] = (bf16_t)gelu_exact(__builtin_fmaf(v0[ks * 8 + j], sb.x, sb.y));
            bfrag1[j] = (bf16_t)gelu_exact(__builtin_fmaf(v1[ks * 8 + j], sb.x, sb.y));
        }
#pragma unroll
        for (int mt = 0; mt < 10; ++mt) {
            bf16x8 afrag = *(const bf16x8*)&wallf[((mt * 5 + ks) * 64 + lane) * 8];
            acc0[mt] = __builtin_amdgcn_mfma_f32_16x16x32_bf16(afrag, bfrag0, acc0[mt], 0, 0, 0);
            acc1[mt] = __builtin_amdgcn_mfma_f32_16x16x32_bf16(afrag, bfrag1, acc1[mt], 0, 0, 0);
        }
    }

    // Epilogue: pack (acc[2kb], acc[2kb+1]) -> permuted 32-block, one 16B store
    // per (kb, row). P row stride = W*32 elements.
    size_t pb = (((size_t)(b * 5) * H + y0) * W + px) * 32 + quad * 8;
#pragma unroll
    for (int kb = 0; kb < 5; ++kb) {
        bf16x8 o0, o1;
#pragma unroll
        for (int r = 0; r < 4; ++r) {
            o0[r]     = (bf16_t)acc0[kb * 2][r];
            o0[r + 4] = (bf16_t)acc0[kb * 2 + 1][r];
            o1[r]     = (bf16_t)acc1[kb * 2][r];
            o1[r + 4] = (bf16_t)acc1[kb * 2 + 1][r];
        }
        *(bf16x8*)&P[pb + (size_t)kb * HW * 32] = o0;
        *(bf16x8*)&P[pb + (size_t)kb * HW * 32 + (size_t)W * 32] = o1;
    }
}

// ---------------------------------------------------------------------------
// Stage 2: out = W_fuse @ shift(P) + b_fuse. Shifts folded into P base address:
//   kb0 (t): (y+1,x)  kb1 (b): (y-1,x)  kb2 (r): (y,x-1)  kb3 (l): (y,x+1)  kb4: (y,x)
// Out-of-range -> zero fragment (drops branch bias at borders, matching pad).
// v3: same row-pairing as stage1 — shared A-fragments, doubled P-load MLP.
// ---------------------------------------------------------------------------
__global__ __launch_bounds__(256, 2) void stage2_kernel(
    char* __restrict__ ws, const float* __restrict__ bfuse,
    float* __restrict__ out)
{
    const bf16_t* __restrict__ wfusef = (const bf16_t*)(ws + WFUSE_OFF);
    const bf16_t* __restrict__ P = (const bf16_t*)ws;

    int wid  = blockIdx.x * 4 + (threadIdx.x >> 6);
    int lane = threadIdx.x & 63;
    int b   = wid / (HP * NT);
    int rem = wid - b * (HP * NT);
    int yp  = rem / NT;
    int t   = rem - yp * NT;
    int y0  = yp * 2, y1 = y0 + 1;
    int nl = lane & 15, quad = lane >> 4;
    int px = t * 16 + nl;

    bf16x8 zero;
#pragma unroll
    for (int j = 0; j < 8; ++j) zero[j] = (bf16_t)0.0f;

    auto ldP = [&](int kb, int yy, int xx) -> bf16x8 {
        return *(const bf16x8*)&P[(((size_t)(b * 5 + kb) * H + yy) * W + xx) * 32 + quad * 8];
    };

    // Issue all 10 shifted B-fragment loads up front; pin them.
    bf16x8 f0[5], f1[5];
    f0[0] = ldP(0, y0 + 1, px);
    f0[1] = ldP(1, y0 - 1 < 0 ? 0 : y0 - 1, px);
    f0[2] = ldP(2, y0, px == 0 ? 0 : px - 1);
    f0[3] = ldP(3, y0, px == W - 1 ? px : px + 1);
    f0[4] = ldP(4, y0, px);
    f1[0] = ldP(0, y1 + 1 >= H ? y1 : y1 + 1, px);
    f1[1] = ldP(1, y1 - 1, px);
    f1[2] = ldP(2, y1, px == 0 ? 0 : px - 1);
    f1[3] = ldP(3, y1, px == W - 1 ? px : px + 1);
    f1[4] = ldP(4, y1, px);
    __builtin_amdgcn_sched_barrier(0);

    // Border masking (in-register; drops branch bias at borders, matching pad).
    if (y0 == 0)     f0[1] = zero;          // row y0-1 invalid
    if (y1 + 1 >= H) f1[0] = zero;          // row y1+1 invalid
    if (px == 0)     { f0[2] = zero; f1[2] = zero; }
    if (px == W - 1) { f0[3] = zero; f1[3] = zero; }

    f32x4 acc0[10], acc1[10];
#pragma unroll
    for (int mt = 0; mt < 10; ++mt) {
        f32x4 bias = *(const f32x4*)&bfuse[mt * 16 + quad * 4];
        acc0[mt] = bias;
        acc1[mt] = bias;
    }

#pragma unroll
    for (int ks = 0; ks < 5; ++ks) {
#pragma unroll
        for (int mt = 0; mt < 10; ++mt) {
            bf16x8 afrag = *(const bf16x8*)&wfusef[((mt * 5 + ks) * 64 + lane) * 8];
            acc0[mt] = __builtin_amdgcn_mfma_f32_16x16x32_bf16(afrag, f0[ks], acc0[mt], 0, 0, 0);
            acc1[mt] = __builtin_amdgcn_mfma_f32_16x16x32_bf16(afrag, f1[ks], acc1[mt], 0, 0, 0);
        }
    }

    size_t ob = (size_t)b * C * HW + (size_t)y0 * W + px;
#pragma unroll
    for (int mt = 0; mt < 10; ++mt) {
#pragma unroll
        for (int r = 0; r < 4; ++r) {
            int m = mt * 16 + quad * 4 + r;
            out[ob + (size_t)m * HW] = acc0[mt][r];
            out[ob + (size_t)m * HW + W] = acc1[mt][r];
        }
    }
}

// ---------------------------------------------------------------------------
extern "C" void kernel_launch(void* const* d_in, const int* in_sizes, int n_in,
                              void* d_out, int out_size, void* d_ws, size_t ws_size,
                              hipStream_t stream)
{
    const float* x     = (const float*)d_in[0];
    const float* gamma = (const float*)d_in[1];
    const float* beta  = (const float*)d_in[2];
    const float* mean  = (const float*)d_in[3];
    const float* var   = (const float*)d_in[4];
    const float* Wt    = (const float*)d_in[5];
    const float* bt    = (const float*)d_in[6];
    const float* Wb    = (const float*)d_in[7];
    const float* bb    = (const float*)d_in[8];
    const float* Wr    = (const float*)d_in[9];
    const float* br    = (const float*)d_in[10];
    const float* Wl    = (const float*)d_in[11];
    const float* bl    = (const float*)d_in[12];
    const float* Wc    = (const float*)d_in[13];
    const float* bc    = (const float*)d_in[14];
    const float* Wfuse = (const float*)d_in[15];
    const float* bfuse = (const float*)d_in[16];

    char* ws = (char*)d_ws;
    float* out = (float*)d_out;

    prep_kernel<<<64, 256, 0, stream>>>(Wt, Wb, Wr, Wl, Wc, bt, bb, br, bl, bc,
                                        Wfuse, gamma, beta, mean, var, ws);

    int nblocks = (BATCH * HP * NT) / 4;   // 12544 row-pair waves / 4 per block
    stage1_kernel<<<nblocks, 256, 0, stream>>>(x, ws);
    stage2_kernel<<<nblocks, 256, 0, stream>>>(ws, bfuse, out);
}